// Round 7
// baseline (464.538 us; speedup 1.0000x reference)
//
#include <hip/hip_runtime.h>
#include <hip/hip_bf16.h>

#define NN 4096
#define DD 512
#define HH 8
#define DH 64
#define BN 8192        // total rows (B*N)
#define PAIRS 16       // B*H

typedef unsigned int uint32;
typedef __attribute__((ext_vector_type(8))) short short8;
typedef __attribute__((ext_vector_type(4))) float f32x4;
typedef __attribute__((ext_vector_type(16))) float f32x16;

#define QSCL 0.18033688f   // (1/8) * log2(e): fold softmax scale + exp2 base into Q

__device__ __forceinline__ float blo(uint32 u) {
    union { uint32 i; float f; } c; c.i = u << 16; return c.f;
}
__device__ __forceinline__ float bhi(uint32 u) {
    union { uint32 i; float f; } c; c.i = u & 0xffff0000u; return c.f;
}
__device__ __forceinline__ unsigned short f2b(float x) {
    union { float f; uint32 u; } c; c.f = x;
    return (unsigned short)((c.u + 0x8000u) >> 16);
}
__device__ __forceinline__ uint32 pack2(float lo, float hi) {
    return (uint32)f2b(lo) | ((uint32)f2b(hi) << 16);
}
__device__ __forceinline__ float fexp2(float x) {
#if __has_builtin(__builtin_amdgcn_exp2f)
    return __builtin_amdgcn_exp2f(x);
#else
    return exp2f(x);
#endif
}

// ---------------------------------------------------------------------------
// dtype probe (verified rounds 2-6): 1 = fp32, 0 = bf16.
// ---------------------------------------------------------------------------
__global__ void detect_dtype(const uint32* __restrict__ xw, uint32* __restrict__ flag) {
    __shared__ int cnt;
    if (threadIdx.x == 0) cnt = 0;
    __syncthreads();
    int c = 0;
    for (int i = threadIdx.x; i < 1024; i += 64) {
        uint32 e = (xw[i] >> 7) & 0xFFu;
        if (e >= 110u && e <= 135u) c++;
    }
    atomicAdd(&cnt, c);
    __syncthreads();
    if (threadIdx.x == 0) *flag = (cnt < 512) ? 1u : 0u;
}

// ---------------------------------------------------------------------------
// Conversion kernels (verified round 3+): normalize once to bf16 / fp32-bias.
// ---------------------------------------------------------------------------
__global__ __launch_bounds__(256) void conv_x(const void* __restrict__ src,
                                              unsigned short* __restrict__ dst,
                                              const uint32* __restrict__ flagp) {
    int i0 = (blockIdx.x * 256 + threadIdx.x) * 8;
    if (*flagp) {
        const float4* s = (const float4*)src;
        float4 a = s[i0 >> 2], b = s[(i0 >> 2) + 1];
        uint4 o;
        o.x = pack2(a.x, a.y); o.y = pack2(a.z, a.w);
        o.z = pack2(b.x, b.y); o.w = pack2(b.z, b.w);
        *(uint4*)(dst + i0) = o;
    } else {
        *(uint4*)(dst + i0) = ((const uint4*)src)[i0 >> 3];
    }
}

__global__ __launch_bounds__(256) void conv_w(const void* s0, const void* s1,
                                              const void* s2, const void* s3,
                                              unsigned short* __restrict__ dst,
                                              const uint32* __restrict__ flagp) {
    int seg = blockIdx.x >> 7;
    const void* src = (seg == 0) ? s0 : (seg == 1) ? s1 : (seg == 2) ? s2 : s3;
    unsigned short* d = dst + (size_t)seg * DD * DD;
    int i0 = ((blockIdx.x & 127) * 256 + threadIdx.x) * 8;
    if (*flagp) {
        const float4* s = (const float4*)src;
        float4 a = s[i0 >> 2], b = s[(i0 >> 2) + 1];
        uint4 o;
        o.x = pack2(a.x, a.y); o.y = pack2(a.z, a.w);
        o.z = pack2(b.x, b.y); o.w = pack2(b.z, b.w);
        *(uint4*)(d + i0) = o;
    } else {
        *(uint4*)(d + i0) = ((const uint4*)src)[i0 >> 3];
    }
}

__global__ __launch_bounds__(256) void conv_b(const void* s0, const void* s1,
                                              const void* s2, const void* s3,
                                              float* __restrict__ dst,
                                              const uint32* __restrict__ flagp) {
    const void* sl[4] = { s0, s1, s2, s3 };
    int fp32mode = (int)*flagp;
    #pragma unroll
    for (int m = 0; m < 4; ++m) {
        #pragma unroll
        for (int j = 0; j < 2; ++j) {
            int i = threadIdx.x * 2 + j;
            float v;
            if (fp32mode) v = ((const float*)sl[m])[i];
            else {
                union { uint32 u; float f; } c;
                c.u = ((uint32)((const unsigned short*)sl[m])[i]) << 16;
                v = c.f;
            }
            dst[m * DD + i] = v;
        }
    }
}

// ---------------------------------------------------------------------------
// QKV projection GEMM (unchanged from round 6, which was correct).
// ---------------------------------------------------------------------------
__global__ __launch_bounds__(256) void qkv_gemm(
    const unsigned short* __restrict__ xb,
    const unsigned short* __restrict__ wsb,
    const float* __restrict__ bsf,
    unsigned short* __restrict__ Qb, unsigned short* __restrict__ Kb,
    unsigned short* __restrict__ VTg)
{
    __shared__ unsigned short As[128 * 40];
    __shared__ unsigned short Bs[128 * 40];
    const int tid = threadIdx.x;
    const int mat = blockIdx.x >> 8;
    const int rem = blockIdx.x & 255;
    const int nt = rem >> 6, mt = rem & 63;
    const int m0 = mt * 128, n0 = nt * 128;
    const int w = tid >> 6, lane = tid & 63, quad = lane >> 4, col = lane & 15;
    const int wr = w >> 1, wc = w & 1;
    const unsigned short* wm = wsb + (size_t)mat * DD * DD;
    const bool qk = (mat < 2);

    f32x4 acc[4][4];
    #pragma unroll
    for (int i = 0; i < 4; ++i)
        #pragma unroll
        for (int j = 0; j < 4; ++j)
            acc[i][j] = (f32x4){0.f, 0.f, 0.f, 0.f};

    for (int kt = 0; kt < 16; ++kt) {
        int k0 = kt * 32;
        __syncthreads();
        #pragma unroll
        for (int it = 0; it < 2; ++it) {
            int idx = tid + it * 256;
            int row = idx >> 2, c4 = idx & 3;
            *(uint4*)&As[row * 40 + c4 * 8] =
                *(const uint4*)(xb + (size_t)(m0 + row) * DD + k0 + c4 * 8);
            *(uint4*)&Bs[row * 40 + c4 * 8] =
                *(const uint4*)(wm + (size_t)(n0 + row) * DD + k0 + c4 * 8);
        }
        __syncthreads();
        if (qk) {
            short8 wf[4], xf[4];
            #pragma unroll
            for (int i = 0; i < 4; ++i)
                wf[i] = *(const short8*)&Bs[(wr * 64 + i * 16 + col) * 40 + quad * 8];
            #pragma unroll
            for (int j = 0; j < 4; ++j)
                xf[j] = *(const short8*)&As[(wc * 64 + j * 16 + col) * 40 + quad * 8];
            #pragma unroll
            for (int i = 0; i < 4; ++i)
                #pragma unroll
                for (int j = 0; j < 4; ++j)
                    acc[i][j] = __builtin_amdgcn_mfma_f32_16x16x32_bf16(
                        wf[i], xf[j], acc[i][j], 0, 0, 0);
        } else {
            short8 xf[4], wf[4];
            #pragma unroll
            for (int i = 0; i < 4; ++i)
                xf[i] = *(const short8*)&As[(wr * 64 + i * 16 + col) * 40 + quad * 8];
            #pragma unroll
            for (int j = 0; j < 4; ++j)
                wf[j] = *(const short8*)&Bs[(wc * 64 + j * 16 + col) * 40 + quad * 8];
            #pragma unroll
            for (int i = 0; i < 4; ++i)
                #pragma unroll
                for (int j = 0; j < 4; ++j)
                    acc[i][j] = __builtin_amdgcn_mfma_f32_16x16x32_bf16(
                        xf[i], wf[j], acc[i][j], 0, 0, 0);
        }
    }

    if (qk) {
        unsigned short* Om = (mat == 0) ? Qb : Kb;
        const float sc = (mat == 0) ? QSCL : 1.f;
        #pragma unroll
        for (int i = 0; i < 4; ++i) {
            int e0 = n0 + wr * 64 + i * 16 + quad * 4;
            float4 bj = *(const float4*)(bsf + mat * DD + e0);
            int h = e0 >> 6, jj0 = e0 & 63;
            #pragma unroll
            for (int j = 0; j < 4; ++j) {
                int g = m0 + wc * 64 + j * 16 + col;
                int b = g >> 12, n = g & (NN - 1);
                uint2 v;
                v.x = pack2((acc[i][j][0] + bj.x) * sc, (acc[i][j][1] + bj.y) * sc);
                v.y = pack2((acc[i][j][2] + bj.z) * sc, (acc[i][j][3] + bj.w) * sc);
                *(uint2*)(Om + ((size_t)((b << 3) + h) * NN + n) * DH + jj0) = v;
            }
        }
    } else {
        #pragma unroll
        for (int j = 0; j < 4; ++j) {
            int e = n0 + wc * 64 + j * 16 + col;
            float bj = bsf[2 * DD + e];
            int h = e >> 6, jj = e & 63;
            #pragma unroll
            for (int i = 0; i < 4; ++i) {
                int g0 = m0 + wr * 64 + i * 16 + quad * 4;
                int b = g0 >> 12, n = g0 & (NN - 1);
                uint2 v;
                v.x = pack2(acc[i][j][0] + bj, acc[i][j][1] + bj);
                v.y = pack2(acc[i][j][2] + bj, acc[i][j][3] + bj);
                *(uint2*)(VTg + ((size_t)((b << 3) + h) * DH + jj) * NN + n) = v;
            }
        }
    }
}

// ---------------------------------------------------------------------------
// Flash attention v5 = round 5's verified zero-conflict wave structure
// (64 q-rows/wave, qs=2, dbuf + register prefetch, static unroll-2 buffers,
// shfl P-exchange, direct register epilogue) at 2-wave blocks:
// 512 blocks = 2 blocks/CU = 8 waves/CU. No cross-wave reduction.
// ---------------------------------------------------------------------------
__global__ __launch_bounds__(128, 2) void attn_mfma(
    const unsigned short* __restrict__ Qb,
    const unsigned short* __restrict__ Kb,
    const unsigned short* __restrict__ VTg,
    unsigned short* __restrict__ Ob)
{
    __shared__ unsigned short Kt[2][64 * 72];   // [key][dim]
    __shared__ unsigned short Vt[2][64 * 72];   // [dim][key]

    const int tid  = threadIdx.x;
    const int w    = tid >> 6;
    const int lane = tid & 63;
    const int m32  = lane & 31;
    const int half = lane >> 5;
    const int pair = blockIdx.x & 15;    // same-pair blocks share an XCD L2
    const int chunk = blockIdx.x >> 4;   // 0..31
    const size_t base = (size_t)pair * NN;
    const int qrow0 = chunk * 128 + w * 64;

    // Q B-frags (Q pre-scaled by log2e/8): B[n=qrow][k=dim]
    short8 qf[2][4];
    #pragma unroll
    for (int qs = 0; qs < 2; ++qs)
        #pragma unroll
        for (int kc = 0; kc < 4; ++kc)
            qf[qs][kc] = *(const short8*)(Qb +
                (base + qrow0 + qs * 32 + m32) * DH + kc * 16 + half * 8);

    f32x16 accO[2][2];
    #pragma unroll
    for (int qs = 0; qs < 2; ++qs)
        #pragma unroll
        for (int dt = 0; dt < 2; ++dt)
            #pragma unroll
            for (int r = 0; r < 16; ++r) accO[qs][dt][r] = 0.f;
    float lsum[2] = { 0.f, 0.f };

    const unsigned short* Kg = Kb + base * DH;
    const unsigned short* Vg = VTg + (size_t)pair * DH * NN;

    // staging: 128 threads x 4 b128 per array per window
    uint4 kpre[4], vpre[4];
    #pragma unroll
    for (int i = 0; i < 4; ++i) {
        int idx = tid + i * 128;
        int row = idx >> 3, c8 = (idx & 7) * 8;
        kpre[i] = *(const uint4*)(Kg + (size_t)row * DH + c8);
        vpre[i] = *(const uint4*)(Vg + (size_t)row * NN + c8);
    }

    #pragma unroll 2
    for (int it = 0; it < NN / 64; ++it) {
        const int buf = it & 1;
        #pragma unroll
        for (int i = 0; i < 4; ++i) {
            int idx = tid + i * 128;
            int row = idx >> 3, c8 = (idx & 7) * 8;
            *(uint4*)&Kt[buf][row * 72 + c8] = kpre[i];
            *(uint4*)&Vt[buf][row * 72 + c8] = vpre[i];
        }
        {   // prefetch next window (wraps harmlessly on last iteration)
            int nw = ((it + 1) & (NN / 64 - 1)) * 64;
            #pragma unroll
            for (int i = 0; i < 4; ++i) {
                int idx = tid + i * 128;
                int row = idx >> 3, c8 = (idx & 7) * 8;
                kpre[i] = *(const uint4*)(Kg + (size_t)(nw + row) * DH + c8);
                vpre[i] = *(const uint4*)(Vg + (size_t)row * NN + nw + c8);
            }
        }
        __syncthreads();

        #pragma unroll
        for (int ktile = 0; ktile < 2; ++ktile) {
            // S^T = K Q^T for 32-key tile
            f32x16 s0, s1;
            #pragma unroll
            for (int r = 0; r < 16; ++r) { s0[r] = 0.f; s1[r] = 0.f; }
            #pragma unroll
            for (int kc = 0; kc < 4; ++kc) {
                short8 kf = *(const short8*)&Kt[buf][(ktile * 32 + m32) * 72 + kc * 16 + half * 8];
                s0 = __builtin_amdgcn_mfma_f32_32x32x16_bf16(kf, qf[0][kc], s0, 0, 0, 0);
                s1 = __builtin_amdgcn_mfma_f32_32x32x16_bf16(kf, qf[1][kc], s1, 0, 0, 0);
            }

            // exp2 + pack + half-wave exchange (verified round 5) -> A-frags
            short8 pf0[2], pf1[2];
            #pragma unroll
            for (int qs = 0; qs < 2; ++qs) {
                const f32x16& s = qs ? s1 : s0;
                float p[16];
                #pragma unroll
                for (int r = 0; r < 16; ++r)
                    p[r] = fexp2(fminf(s[r], 80.f));
                lsum[qs] += ((p[0] + p[1]) + (p[2] + p[3])) + ((p[4] + p[5]) + (p[6] + p[7]))
                          + ((p[8] + p[9]) + (p[10] + p[11])) + ((p[12] + p[13]) + (p[14] + p[15]));
                uint32 d[8];
                #pragma unroll
                for (int i = 0; i < 8; ++i) d[i] = pack2(p[2 * i], p[2 * i + 1]);
                uint32 t0 = (uint32)__shfl_xor((int)(half ? d[0] : d[2]), 32);
                uint32 t1 = (uint32)__shfl_xor((int)(half ? d[1] : d[3]), 32);
                uint32 t2 = (uint32)__shfl_xor((int)(half ? d[4] : d[6]), 32);
                uint32 t3 = (uint32)__shfl_xor((int)(half ? d[5] : d[7]), 32);
                union { uint32 u[4]; short8 s8; } c0, c1;
                c0.u[0] = half ? t0 : d[0]; c0.u[1] = half ? t1 : d[1];
                c0.u[2] = half ? d[2] : t0; c0.u[3] = half ? d[3] : t1;
                c1.u[0] = half ? t2 : d[4]; c1.u[1] = half ? t3 : d[5];
                c1.u[2] = half ? d[6] : t2; c1.u[3] = half ? d[7] : t3;
                if (qs == 0) { pf0[0] = c0.s8; pf0[1] = c1.s8; }
                else         { pf1[0] = c0.s8; pf1[1] = c1.s8; }
            }

            // O += P V : vf shared across both q-sets
            #pragma unroll
            for (int c = 0; c < 2; ++c) {
                int ch = ktile * 2 + c;
                #pragma unroll
                for (int dt = 0; dt < 2; ++dt) {
                    short8 vf = *(const short8*)&Vt[buf][(dt * 32 + m32) * 72 + ch * 16 + half * 8];
                    accO[0][dt] = __builtin_amdgcn_mfma_f32_32x32x16_bf16(pf0[c], vf, accO[0][dt], 0, 0, 0);
                    accO[1][dt] = __builtin_amdgcn_mfma_f32_32x32x16_bf16(pf1[c], vf, accO[1][dt], 0, 0, 0);
                }
            }
        }
    }

    // rowsum reduce across halves; direct register epilogue (verified round 5)
    float inv[2];
    #pragma unroll
    for (int qs = 0; qs < 2; ++qs) {
        float l = lsum[qs] + __shfl_xor(lsum[qs], 32);
        inv[qs] = 1.f / l;
    }

    #pragma unroll
    for (int qs = 0; qs < 2; ++qs) {
        float invr[16];
        #pragma unroll
        for (int r = 0; r < 16; ++r) {
            int rowq = (r & 3) + 8 * (r >> 2) + 4 * half;
            invr[r] = __shfl(inv[qs], rowq);
        }
        #pragma unroll
        for (int dt = 0; dt < 2; ++dt)
            #pragma unroll
            for (int r = 0; r < 16; ++r) {
                int rowq = (r & 3) + 8 * (r >> 2) + 4 * half;
                Ob[(base + qrow0 + qs * 32 + rowq) * DH + dt * 32 + m32] =
                    f2b(accO[qs][dt][r] * invr[r]);
            }
    }
}

// ---------------------------------------------------------------------------
// Output projection GEMM (unchanged from round 6).
// ---------------------------------------------------------------------------
__global__ __launch_bounds__(256) void out_gemm(
    const unsigned short* __restrict__ Ob,
    const unsigned short* __restrict__ wob,
    const float* __restrict__ bof,
    const uint32* __restrict__ flagp,
    void* __restrict__ outp)
{
    __shared__ unsigned short As[128 * 40];
    __shared__ unsigned short Bs[128 * 40];
    const int tid = threadIdx.x;
    const int nt = blockIdx.x >> 6, mt = blockIdx.x & 63;
    const int m0 = mt * 128, n0 = nt * 128;
    const int w = tid >> 6, lane = tid & 63, quad = lane >> 4, col = lane & 15;
    const int wr = w >> 1, wc = w & 1;
    const int fp32mode = (int)*flagp;

    f32x4 acc[4][4];
    #pragma unroll
    for (int i = 0; i < 4; ++i)
        #pragma unroll
        for (int j = 0; j < 4; ++j)
            acc[i][j] = (f32x4){0.f, 0.f, 0.f, 0.f};

    for (int kt = 0; kt < 16; ++kt) {
        int k0 = kt * 32;
        int h = k0 >> 6, koff = k0 & 63;
        __syncthreads();
        #pragma unroll
        for (int it = 0; it < 2; ++it) {
            int idx = tid + it * 256;
            int row = idx >> 2, c4 = idx & 3;
            int g = m0 + row, b = g >> 12, n = g & (NN - 1);
            *(uint4*)&As[row * 40 + c4 * 8] = *(const uint4*)(Ob +
                ((size_t)((b << 3) + h) * NN + n) * DH + koff + c4 * 8);
            *(uint4*)&Bs[row * 40 + c4 * 8] =
                *(const uint4*)(wob + (size_t)(n0 + row) * DD + k0 + c4 * 8);
        }
        __syncthreads();
        short8 wf[4], yf[4];
        #pragma unroll
        for (int i = 0; i < 4; ++i)
            wf[i] = *(const short8*)&Bs[(wr * 64 + i * 16 + col) * 40 + quad * 8];
        #pragma unroll
        for (int j = 0; j < 4; ++j)
            yf[j] = *(const short8*)&As[(wc * 64 + j * 16 + col) * 40 + quad * 8];
        #pragma unroll
        for (int i = 0; i < 4; ++i)
            #pragma unroll
            for (int j = 0; j < 4; ++j)
                acc[i][j] = __builtin_amdgcn_mfma_f32_16x16x32_bf16(
                    wf[i], yf[j], acc[i][j], 0, 0, 0);
    }

    #pragma unroll
    for (int i = 0; i < 4; ++i) {
        int e0 = n0 + wr * 64 + i * 16 + quad * 4;
        float4 bj = *(const float4*)(bof + e0);
        #pragma unroll
        for (int j = 0; j < 4; ++j) {
            int g = m0 + wc * 64 + j * 16 + col;
            float v0 = acc[i][j][0] + bj.x;
            float v1 = acc[i][j][1] + bj.y;
            float v2 = acc[i][j][2] + bj.z;
            float v3 = acc[i][j][3] + bj.w;
            if (fp32mode) {
                float4 o; o.x = v0; o.y = v1; o.z = v2; o.w = v3;
                *(float4*)((float*)outp + (size_t)g * DD + e0) = o;
            } else {
                uint2 o; o.x = pack2(v0, v1); o.y = pack2(v2, v3);
                *(uint2*)((unsigned short*)outp + (size_t)g * DD + e0) = o;
            }
        }
    }
}

// ---------------------------------------------------------------------------
extern "C" void kernel_launch(void* const* d_in, const int* in_sizes, int n_in,
                              void* d_out, int out_size, void* d_ws, size_t ws_size,
                              hipStream_t stream) {
    char* p = (char*)d_ws;
    uint32* flag = (uint32*)p;                  p += 256;
    unsigned short* xb  = (unsigned short*)p;   p += (size_t)BN * DD * 2;
    unsigned short* wsb = (unsigned short*)p;   p += (size_t)4 * DD * DD * 2;
    float*          bsf = (float*)p;            p += (size_t)4 * DD * 4;
    unsigned short* Qb  = (unsigned short*)p;   p += (size_t)PAIRS * NN * DH * 2;
    unsigned short* Kb  = (unsigned short*)p;   p += (size_t)PAIRS * NN * DH * 2;
    unsigned short* VTg = (unsigned short*)p;   p += (size_t)PAIRS * NN * DH * 2;
    unsigned short* Ob  = (unsigned short*)p;   p += (size_t)PAIRS * NN * DH * 2;

    detect_dtype<<<1, 64, 0, stream>>>((const uint32*)d_in[0], flag);
    conv_x<<<BN * DD / 2048, 256, 0, stream>>>(d_in[0], xb, flag);
    conv_w<<<512, 256, 0, stream>>>(d_in[1], d_in[3], d_in[5], d_in[7], wsb, flag);
    conv_b<<<1, 256, 0, stream>>>(d_in[2], d_in[4], d_in[6], d_in[8], bsf, flag);
    qkv_gemm<<<768, 256, 0, stream>>>(xb, wsb, bsf, Qb, Kb, VTg);
    attn_mfma<<<512, 128, 0, stream>>>(Qb, Kb, VTg, Ob);
    out_gemm<<<256, 256, 0, stream>>>(Ob, wsb + (size_t)3 * DD * DD,
                                      bsf + 3 * DD, flag, d_out);
}

// Round 8
// 280.504 us; speedup vs baseline: 1.6561x; 1.6561x over previous
//
#include <hip/hip_runtime.h>
#include <hip/hip_bf16.h>

#define NN 4096
#define DD 512
#define HH 8
#define DH 64
#define BN 8192        // total rows (B*N)
#define PAIRS 16       // B*H
#define TROWS 65536    // PAIRS*NN

typedef unsigned int uint32;
typedef __attribute__((ext_vector_type(8))) short short8;
typedef __attribute__((ext_vector_type(4))) float f32x4;
typedef __attribute__((ext_vector_type(16))) float f32x16;

#define QSCL 0.18033688f   // (1/8) * log2(e): fold softmax scale + exp2 base into Q

__device__ __forceinline__ float blo(uint32 u) {
    union { uint32 i; float f; } c; c.i = u << 16; return c.f;
}
__device__ __forceinline__ float bhi(uint32 u) {
    union { uint32 i; float f; } c; c.i = u & 0xffff0000u; return c.f;
}
__device__ __forceinline__ unsigned short f2b(float x) {
    union { float f; uint32 u; } c; c.f = x;
    return (unsigned short)((c.u + 0x8000u) >> 16);
}
__device__ __forceinline__ uint32 pack2(float lo, float hi) {
    return (uint32)f2b(lo) | ((uint32)f2b(hi) << 16);
}
__device__ __forceinline__ float fexp2(float x) {
#if __has_builtin(__builtin_amdgcn_exp2f)
    return __builtin_amdgcn_exp2f(x);
#else
    return exp2f(x);
#endif
}

// ---------------------------------------------------------------------------
// dtype probe (verified rounds 2-7): 1 = fp32, 0 = bf16.
// ---------------------------------------------------------------------------
__global__ void detect_dtype(const uint32* __restrict__ xw, uint32* __restrict__ flag) {
    __shared__ int cnt;
    if (threadIdx.x == 0) cnt = 0;
    __syncthreads();
    int c = 0;
    for (int i = threadIdx.x; i < 1024; i += 64) {
        uint32 e = (xw[i] >> 7) & 0xFFu;
        if (e >= 110u && e <= 135u) c++;
    }
    atomicAdd(&cnt, c);
    __syncthreads();
    if (threadIdx.x == 0) *flag = (cnt < 512) ? 1u : 0u;
}

// ---------------------------------------------------------------------------
// Conversion kernels (verified round 3+).
// ---------------------------------------------------------------------------
__global__ __launch_bounds__(256) void conv_x(const void* __restrict__ src,
                                              unsigned short* __restrict__ dst,
                                              const uint32* __restrict__ flagp) {
    int i0 = (blockIdx.x * 256 + threadIdx.x) * 8;
    if (*flagp) {
        const float4* s = (const float4*)src;
        float4 a = s[i0 >> 2], b = s[(i0 >> 2) + 1];
        uint4 o;
        o.x = pack2(a.x, a.y); o.y = pack2(a.z, a.w);
        o.z = pack2(b.x, b.y); o.w = pack2(b.z, b.w);
        *(uint4*)(dst + i0) = o;
    } else {
        *(uint4*)(dst + i0) = ((const uint4*)src)[i0 >> 3];
    }
}

__global__ __launch_bounds__(256) void conv_w(const void* s0, const void* s1,
                                              const void* s2, const void* s3,
                                              unsigned short* __restrict__ dst,
                                              const uint32* __restrict__ flagp) {
    int seg = blockIdx.x >> 7;
    const void* src = (seg == 0) ? s0 : (seg == 1) ? s1 : (seg == 2) ? s2 : s3;
    unsigned short* d = dst + (size_t)seg * DD * DD;
    int i0 = ((blockIdx.x & 127) * 256 + threadIdx.x) * 8;
    if (*flagp) {
        const float4* s = (const float4*)src;
        float4 a = s[i0 >> 2], b = s[(i0 >> 2) + 1];
        uint4 o;
        o.x = pack2(a.x, a.y); o.y = pack2(a.z, a.w);
        o.z = pack2(b.x, b.y); o.w = pack2(b.z, b.w);
        *(uint4*)(d + i0) = o;
    } else {
        *(uint4*)(d + i0) = ((const uint4*)src)[i0 >> 3];
    }
}

__global__ __launch_bounds__(256) void conv_b(const void* s0, const void* s1,
                                              const void* s2, const void* s3,
                                              float* __restrict__ dst,
                                              const uint32* __restrict__ flagp) {
    const void* sl[4] = { s0, s1, s2, s3 };
    int fp32mode = (int)*flagp;
    #pragma unroll
    for (int m = 0; m < 4; ++m) {
        #pragma unroll
        for (int j = 0; j < 2; ++j) {
            int i = threadIdx.x * 2 + j;
            float v;
            if (fp32mode) v = ((const float*)sl[m])[i];
            else {
                union { uint32 u; float f; } c;
                c.u = ((uint32)((const unsigned short*)sl[m])[i]) << 16;
                v = c.f;
            }
            dst[m * DD + i] = v;
        }
    }
}

// ---------------------------------------------------------------------------
// QKV projection GEMM (unchanged, verified).
// ---------------------------------------------------------------------------
__global__ __launch_bounds__(256) void qkv_gemm(
    const unsigned short* __restrict__ xb,
    const unsigned short* __restrict__ wsb,
    const float* __restrict__ bsf,
    unsigned short* __restrict__ Qb, unsigned short* __restrict__ Kb,
    unsigned short* __restrict__ VTg)
{
    __shared__ unsigned short As[128 * 40];
    __shared__ unsigned short Bs[128 * 40];
    const int tid = threadIdx.x;
    const int mat = blockIdx.x >> 8;
    const int rem = blockIdx.x & 255;
    const int nt = rem >> 6, mt = rem & 63;
    const int m0 = mt * 128, n0 = nt * 128;
    const int w = tid >> 6, lane = tid & 63, quad = lane >> 4, col = lane & 15;
    const int wr = w >> 1, wc = w & 1;
    const unsigned short* wm = wsb + (size_t)mat * DD * DD;
    const bool qk = (mat < 2);

    f32x4 acc[4][4];
    #pragma unroll
    for (int i = 0; i < 4; ++i)
        #pragma unroll
        for (int j = 0; j < 4; ++j)
            acc[i][j] = (f32x4){0.f, 0.f, 0.f, 0.f};

    for (int kt = 0; kt < 16; ++kt) {
        int k0 = kt * 32;
        __syncthreads();
        #pragma unroll
        for (int it = 0; it < 2; ++it) {
            int idx = tid + it * 256;
            int row = idx >> 2, c4 = idx & 3;
            *(uint4*)&As[row * 40 + c4 * 8] =
                *(const uint4*)(xb + (size_t)(m0 + row) * DD + k0 + c4 * 8);
            *(uint4*)&Bs[row * 40 + c4 * 8] =
                *(const uint4*)(wm + (size_t)(n0 + row) * DD + k0 + c4 * 8);
        }
        __syncthreads();
        if (qk) {
            short8 wf[4], xf[4];
            #pragma unroll
            for (int i = 0; i < 4; ++i)
                wf[i] = *(const short8*)&Bs[(wr * 64 + i * 16 + col) * 40 + quad * 8];
            #pragma unroll
            for (int j = 0; j < 4; ++j)
                xf[j] = *(const short8*)&As[(wc * 64 + j * 16 + col) * 40 + quad * 8];
            #pragma unroll
            for (int i = 0; i < 4; ++i)
                #pragma unroll
                for (int j = 0; j < 4; ++j)
                    acc[i][j] = __builtin_amdgcn_mfma_f32_16x16x32_bf16(
                        wf[i], xf[j], acc[i][j], 0, 0, 0);
        } else {
            short8 xf[4], wf[4];
            #pragma unroll
            for (int i = 0; i < 4; ++i)
                xf[i] = *(const short8*)&As[(wr * 64 + i * 16 + col) * 40 + quad * 8];
            #pragma unroll
            for (int j = 0; j < 4; ++j)
                wf[j] = *(const short8*)&Bs[(wc * 64 + j * 16 + col) * 40 + quad * 8];
            #pragma unroll
            for (int i = 0; i < 4; ++i)
                #pragma unroll
                for (int j = 0; j < 4; ++j)
                    acc[i][j] = __builtin_amdgcn_mfma_f32_16x16x32_bf16(
                        xf[i], wf[j], acc[i][j], 0, 0, 0);
        }
    }

    if (qk) {
        unsigned short* Om = (mat == 0) ? Qb : Kb;
        const float sc = (mat == 0) ? QSCL : 1.f;
        #pragma unroll
        for (int i = 0; i < 4; ++i) {
            int e0 = n0 + wr * 64 + i * 16 + quad * 4;
            float4 bj = *(const float4*)(bsf + mat * DD + e0);
            int h = e0 >> 6, jj0 = e0 & 63;
            #pragma unroll
            for (int j = 0; j < 4; ++j) {
                int g = m0 + wc * 64 + j * 16 + col;
                int b = g >> 12, n = g & (NN - 1);
                uint2 v;
                v.x = pack2((acc[i][j][0] + bj.x) * sc, (acc[i][j][1] + bj.y) * sc);
                v.y = pack2((acc[i][j][2] + bj.z) * sc, (acc[i][j][3] + bj.w) * sc);
                *(uint2*)(Om + ((size_t)((b << 3) + h) * NN + n) * DH + jj0) = v;
            }
        }
    } else {
        #pragma unroll
        for (int j = 0; j < 4; ++j) {
            int e = n0 + wc * 64 + j * 16 + col;
            float bj = bsf[2 * DD + e];
            int h = e >> 6, jj = e & 63;
            #pragma unroll
            for (int i = 0; i < 4; ++i) {
                int g0 = m0 + wr * 64 + i * 16 + quad * 4;
                int b = g0 >> 12, n = g0 & (NN - 1);
                uint2 v;
                v.x = pack2(acc[i][j][0] + bj, acc[i][j][1] + bj);
                v.y = pack2(acc[i][j][2] + bj, acc[i][j][3] + bj);
                *(uint2*)(VTg + ((size_t)((b << 3) + h) * DH + jj) * NN + n) = v;
            }
        }
    }
}

// ---------------------------------------------------------------------------
// Flash attention v6 = round 5's verified zero-conflict kernel (4 waves x
// 64 q-rows, 256 threads, static unroll-2 dbuf, register prefetch, shfl
// P-exchange) + key-split across blocks: each block does 32 of 64 windows,
// writes fp32 partial O and l. 512 blocks = 2/CU = 8 waves/CU.
// ---------------------------------------------------------------------------
__global__ __launch_bounds__(256, 2) void attn_mfma(
    const unsigned short* __restrict__ Qb,
    const unsigned short* __restrict__ Kb,
    const unsigned short* __restrict__ VTg,
    float* __restrict__ Op,            // [2][TROWS][DH]
    float* __restrict__ Lp)            // [2][TROWS]
{
    __shared__ unsigned short Kt[2][64 * 72];   // [key][dim]
    __shared__ unsigned short Vt[2][64 * 72];   // [dim][key]

    const int tid  = threadIdx.x;
    const int w    = tid >> 6;
    const int lane = tid & 63;
    const int m32  = lane & 31;
    const int half = lane >> 5;
    const int pair = blockIdx.x & 15;          // same-pair blocks share an XCD
    const int chunk = (blockIdx.x >> 4) & 15;  // 0..15
    const int kh   = blockIdx.x >> 8;          // key half: 0 or 1
    const size_t base = (size_t)pair * NN;
    const int qrow0 = chunk * 256 + w * 64;
    const int khbase = kh * (NN / 2);

    // Q B-frags (Q pre-scaled by log2e/8): B[n=qrow][k=dim]
    short8 qf[2][4];
    #pragma unroll
    for (int qs = 0; qs < 2; ++qs)
        #pragma unroll
        for (int kc = 0; kc < 4; ++kc)
            qf[qs][kc] = *(const short8*)(Qb +
                (base + qrow0 + qs * 32 + m32) * DH + kc * 16 + half * 8);

    f32x16 accO[2][2];
    #pragma unroll
    for (int qs = 0; qs < 2; ++qs)
        #pragma unroll
        for (int dt = 0; dt < 2; ++dt)
            #pragma unroll
            for (int r = 0; r < 16; ++r) accO[qs][dt][r] = 0.f;
    float lsum[2] = { 0.f, 0.f };

    const unsigned short* Kg = Kb + base * DH;
    const unsigned short* Vg = VTg + (size_t)pair * DH * NN;

    // staging (exact round-5 pattern): 2 b128 per thread per array
    const int kr0 = tid >> 3,          kc0 = (tid & 7) * 8;
    const int kr1 = (tid + 256) >> 3,  kc1 = ((tid + 256) & 7) * 8;

    uint4 kpre[2], vpre[2];
    kpre[0] = *(const uint4*)(Kg + (size_t)(khbase + kr0) * DH + kc0);
    kpre[1] = *(const uint4*)(Kg + (size_t)(khbase + kr1) * DH + kc1);
    vpre[0] = *(const uint4*)(Vg + (size_t)kr0 * NN + khbase + kc0);
    vpre[1] = *(const uint4*)(Vg + (size_t)kr1 * NN + khbase + kc1);

    #pragma unroll 2
    for (int it = 0; it < NN / 128; ++it) {     // 32 windows of 64 keys
        const int buf = it & 1;
        *(uint4*)&Kt[buf][kr0 * 72 + kc0] = kpre[0];
        *(uint4*)&Kt[buf][kr1 * 72 + kc1] = kpre[1];
        *(uint4*)&Vt[buf][kr0 * 72 + kc0] = vpre[0];
        *(uint4*)&Vt[buf][kr1 * 72 + kc1] = vpre[1];
        {   // prefetch next window (wraps harmlessly on last iteration)
            int nw = khbase + (((it + 1) & (NN / 128 - 1)) * 64);
            kpre[0] = *(const uint4*)(Kg + (size_t)(nw + kr0) * DH + kc0);
            kpre[1] = *(const uint4*)(Kg + (size_t)(nw + kr1) * DH + kc1);
            vpre[0] = *(const uint4*)(Vg + (size_t)kr0 * NN + nw + kc0);
            vpre[1] = *(const uint4*)(Vg + (size_t)kr1 * NN + nw + kc1);
        }
        __syncthreads();

        #pragma unroll
        for (int ktile = 0; ktile < 2; ++ktile) {
            // S^T = K Q^T for 32-key tile
            f32x16 s0, s1;
            #pragma unroll
            for (int r = 0; r < 16; ++r) { s0[r] = 0.f; s1[r] = 0.f; }
            #pragma unroll
            for (int kc = 0; kc < 4; ++kc) {
                short8 kf = *(const short8*)&Kt[buf][(ktile * 32 + m32) * 72 + kc * 16 + half * 8];
                s0 = __builtin_amdgcn_mfma_f32_32x32x16_bf16(kf, qf[0][kc], s0, 0, 0, 0);
                s1 = __builtin_amdgcn_mfma_f32_32x32x16_bf16(kf, qf[1][kc], s1, 0, 0, 0);
            }

            // exp2 + pack + half-wave exchange (verified round 5) -> A-frags
            short8 pf0[2], pf1[2];
            #pragma unroll
            for (int qs = 0; qs < 2; ++qs) {
                const f32x16& s = qs ? s1 : s0;
                float p[16];
                #pragma unroll
                for (int r = 0; r < 16; ++r)
                    p[r] = fexp2(fminf(s[r], 80.f));
                lsum[qs] += ((p[0] + p[1]) + (p[2] + p[3])) + ((p[4] + p[5]) + (p[6] + p[7]))
                          + ((p[8] + p[9]) + (p[10] + p[11])) + ((p[12] + p[13]) + (p[14] + p[15]));
                uint32 d[8];
                #pragma unroll
                for (int i = 0; i < 8; ++i) d[i] = pack2(p[2 * i], p[2 * i + 1]);
                uint32 t0 = (uint32)__shfl_xor((int)(half ? d[0] : d[2]), 32);
                uint32 t1 = (uint32)__shfl_xor((int)(half ? d[1] : d[3]), 32);
                uint32 t2 = (uint32)__shfl_xor((int)(half ? d[4] : d[6]), 32);
                uint32 t3 = (uint32)__shfl_xor((int)(half ? d[5] : d[7]), 32);
                union { uint32 u[4]; short8 s8; } c0, c1;
                c0.u[0] = half ? t0 : d[0]; c0.u[1] = half ? t1 : d[1];
                c0.u[2] = half ? d[2] : t0; c0.u[3] = half ? d[3] : t1;
                c1.u[0] = half ? t2 : d[4]; c1.u[1] = half ? t3 : d[5];
                c1.u[2] = half ? d[6] : t2; c1.u[3] = half ? d[7] : t3;
                if (qs == 0) { pf0[0] = c0.s8; pf0[1] = c1.s8; }
                else         { pf1[0] = c0.s8; pf1[1] = c1.s8; }
            }

            // O += P V
            #pragma unroll
            for (int c = 0; c < 2; ++c) {
                int ch = ktile * 2 + c;
                #pragma unroll
                for (int dt = 0; dt < 2; ++dt) {
                    short8 vf = *(const short8*)&Vt[buf][(dt * 32 + m32) * 72 + ch * 16 + half * 8];
                    accO[0][dt] = __builtin_amdgcn_mfma_f32_32x32x16_bf16(pf0[c], vf, accO[0][dt], 0, 0, 0);
                    accO[1][dt] = __builtin_amdgcn_mfma_f32_32x32x16_bf16(pf1[c], vf, accO[1][dt], 0, 0, 0);
                }
            }
        }
    }

    // epilogue: write fp32 partial O and l for this key half
    lsum[0] += __shfl_xor(lsum[0], 32);
    lsum[1] += __shfl_xor(lsum[1], 32);

    const int rowbase = (int)base + qrow0;
    float* OpH = Op + (size_t)kh * TROWS * DH;
    #pragma unroll
    for (int qs = 0; qs < 2; ++qs) {
        #pragma unroll
        for (int dt = 0; dt < 2; ++dt)
            #pragma unroll
            for (int r = 0; r < 16; ++r) {
                int rowq = (r & 3) + 8 * (r >> 2) + 4 * half;
                OpH[(size_t)(rowbase + qs * 32 + rowq) * DH + dt * 32 + m32] =
                    accO[qs][dt][r];
            }
        if (half == 0)
            Lp[(size_t)kh * TROWS + rowbase + qs * 32 + m32] = lsum[qs];
    }
}

// ---------------------------------------------------------------------------
// Combine kernel: O = (O0 + O1) / (l0 + l1), pack bf16.
// 512 blocks x 256 threads; 2 threads per row, 32 dims each.
// ---------------------------------------------------------------------------
__global__ __launch_bounds__(256) void attn_combine(
    const float* __restrict__ Op, const float* __restrict__ Lp,
    unsigned short* __restrict__ Ob)
{
    const int t = blockIdx.x * 256 + threadIdx.x;
    const int row = t >> 1;
    const int d0 = (t & 1) * 32;
    const float rinv = 1.f / (Lp[row] + Lp[TROWS + row]);
    const float4* p0 = (const float4*)(Op + (size_t)row * DH + d0);
    const float4* p1 = (const float4*)(Op + (size_t)TROWS * DH + (size_t)row * DH + d0);
    uint32 pk[16];
    #pragma unroll
    for (int i = 0; i < 8; ++i) {
        float4 a = p0[i], b = p1[i];
        float v0 = (a.x + b.x) * rinv, v1 = (a.y + b.y) * rinv;
        float v2 = (a.z + b.z) * rinv, v3 = (a.w + b.w) * rinv;
        pk[2 * i]     = pack2(v0, v1);
        pk[2 * i + 1] = pack2(v2, v3);
    }
    uint4* po = (uint4*)(Ob + (size_t)row * DH + d0);
    po[0] = *(uint4*)&pk[0];
    po[1] = *(uint4*)&pk[4];
    po[2] = *(uint4*)&pk[8];
    po[3] = *(uint4*)&pk[12];
}

// ---------------------------------------------------------------------------
// Output projection GEMM (unchanged, verified).
// ---------------------------------------------------------------------------
__global__ __launch_bounds__(256) void out_gemm(
    const unsigned short* __restrict__ Ob,
    const unsigned short* __restrict__ wob,
    const float* __restrict__ bof,
    const uint32* __restrict__ flagp,
    void* __restrict__ outp)
{
    __shared__ unsigned short As[128 * 40];
    __shared__ unsigned short Bs[128 * 40];
    const int tid = threadIdx.x;
    const int nt = blockIdx.x >> 6, mt = blockIdx.x & 63;
    const int m0 = mt * 128, n0 = nt * 128;
    const int w = tid >> 6, lane = tid & 63, quad = lane >> 4, col = lane & 15;
    const int wr = w >> 1, wc = w & 1;
    const int fp32mode = (int)*flagp;

    f32x4 acc[4][4];
    #pragma unroll
    for (int i = 0; i < 4; ++i)
        #pragma unroll
        for (int j = 0; j < 4; ++j)
            acc[i][j] = (f32x4){0.f, 0.f, 0.f, 0.f};

    for (int kt = 0; kt < 16; ++kt) {
        int k0 = kt * 32;
        int h = k0 >> 6, koff = k0 & 63;
        __syncthreads();
        #pragma unroll
        for (int it = 0; it < 2; ++it) {
            int idx = tid + it * 256;
            int row = idx >> 2, c4 = idx & 3;
            int g = m0 + row, b = g >> 12, n = g & (NN - 1);
            *(uint4*)&As[row * 40 + c4 * 8] = *(const uint4*)(Ob +
                ((size_t)((b << 3) + h) * NN + n) * DH + koff + c4 * 8);
            *(uint4*)&Bs[row * 40 + c4 * 8] =
                *(const uint4*)(wob + (size_t)(n0 + row) * DD + k0 + c4 * 8);
        }
        __syncthreads();
        short8 wf[4], yf[4];
        #pragma unroll
        for (int i = 0; i < 4; ++i)
            wf[i] = *(const short8*)&Bs[(wr * 64 + i * 16 + col) * 40 + quad * 8];
        #pragma unroll
        for (int j = 0; j < 4; ++j)
            yf[j] = *(const short8*)&As[(wc * 64 + j * 16 + col) * 40 + quad * 8];
        #pragma unroll
        for (int i = 0; i < 4; ++i)
            #pragma unroll
            for (int j = 0; j < 4; ++j)
                acc[i][j] = __builtin_amdgcn_mfma_f32_16x16x32_bf16(
                    wf[i], yf[j], acc[i][j], 0, 0, 0);
    }

    #pragma unroll
    for (int i = 0; i < 4; ++i) {
        int e0 = n0 + wr * 64 + i * 16 + quad * 4;
        float4 bj = *(const float4*)(bof + e0);
        #pragma unroll
        for (int j = 0; j < 4; ++j) {
            int g = m0 + wc * 64 + j * 16 + col;
            float v0 = acc[i][j][0] + bj.x;
            float v1 = acc[i][j][1] + bj.y;
            float v2 = acc[i][j][2] + bj.z;
            float v3 = acc[i][j][3] + bj.w;
            if (fp32mode) {
                float4 o; o.x = v0; o.y = v1; o.z = v2; o.w = v3;
                *(float4*)((float*)outp + (size_t)g * DD + e0) = o;
            } else {
                uint2 o; o.x = pack2(v0, v1); o.y = pack2(v2, v3);
                *(uint2*)((unsigned short*)outp + (size_t)g * DD + e0) = o;
            }
        }
    }
}

// ---------------------------------------------------------------------------
extern "C" void kernel_launch(void* const* d_in, const int* in_sizes, int n_in,
                              void* d_out, int out_size, void* d_ws, size_t ws_size,
                              hipStream_t stream) {
    char* p = (char*)d_ws;
    uint32* flag = (uint32*)p;                  p += 256;
    unsigned short* xb  = (unsigned short*)p;   p += (size_t)BN * DD * 2;        // 8 MB
    unsigned short* wsb = (unsigned short*)p;   p += (size_t)4 * DD * DD * 2;    // 2 MB
    float*          bsf = (float*)p;            p += (size_t)4 * DD * 4;         // 8 KB
    unsigned short* Qb  = (unsigned short*)p;   p += (size_t)TROWS * DH * 2;     // 8 MB
    unsigned short* Kb  = (unsigned short*)p;   p += (size_t)TROWS * DH * 2;     // 8 MB
    unsigned short* VTg = (unsigned short*)p;   p += (size_t)TROWS * DH * 2;     // 8 MB
    unsigned short* Ob  = (unsigned short*)p;   p += (size_t)TROWS * DH * 2;     // 8 MB
    float*          Op  = (float*)p;            p += (size_t)2 * TROWS * DH * 4; // 32 MB
    float*          Lp  = (float*)p;            p += (size_t)2 * TROWS * 4;      // 0.5 MB

    detect_dtype<<<1, 64, 0, stream>>>((const uint32*)d_in[0], flag);
    conv_x<<<BN * DD / 2048, 256, 0, stream>>>(d_in[0], xb, flag);
    conv_w<<<512, 256, 0, stream>>>(d_in[1], d_in[3], d_in[5], d_in[7], wsb, flag);
    conv_b<<<1, 256, 0, stream>>>(d_in[2], d_in[4], d_in[6], d_in[8], bsf, flag);
    qkv_gemm<<<768, 256, 0, stream>>>(xb, wsb, bsf, Qb, Kb, VTg);
    attn_mfma<<<512, 256, 0, stream>>>(Qb, Kb, VTg, Op, Lp);
    attn_combine<<<512, 256, 0, stream>>>(Op, Lp, Ob);
    out_gemm<<<256, 256, 0, stream>>>(Ob, wsb + (size_t)3 * DD * DD,
                                      bsf + 3 * DD, flag, d_out);
}